// Round 3
// baseline (187.714 us; speedup 1.0000x reference)
//
#include <hip/hip_runtime.h>

#define BB 4
#define SS 16
#define NH 32
#define NKV 8
#define HD 128
#define PAST 8192
#define KVLEN 8208
#define KSPLIT 8
#define NSPLIT 18
#define NTILE 15
#define TK 32   // keys per tile; NSPLIT*NTILE*TK = 8640 >= 8208

typedef __attribute__((ext_vector_type(8))) short short8;
typedef __attribute__((ext_vector_type(4))) float f32x4;

__device__ __forceinline__ unsigned short f2bf(float f) {
  unsigned u = __float_as_uint(f);
  u = (u + 0x7FFFu + ((u >> 16) & 1u)) >> 16;
  return (unsigned short)u;
}
__device__ __forceinline__ float bf2f(unsigned short h) {
  return __uint_as_float(((unsigned)h) << 16);
}
__device__ __forceinline__ unsigned pk2bf(float a, float b) {
  return (unsigned)f2bf(a) | ((unsigned)f2bf(b) << 16);
}
__device__ __forceinline__ float getc(const float4& v, int c) {
  return c == 0 ? v.x : c == 1 ? v.y : c == 2 ? v.z : v.w;
}

// LDS-ordering barrier that does NOT drain vmcnt.
__device__ __forceinline__ void bar_lds() {
  asm volatile("s_waitcnt lgkmcnt(0)" ::: "memory");
  __builtin_amdgcn_s_barrier();
  asm volatile("" ::: "memory");
}
__device__ __forceinline__ void wait_lds() {
  asm volatile("s_waitcnt lgkmcnt(0)" ::: "memory");
}

// async global->LDS, 16B per lane, dest = uniform base + lane*16
#define GLOAD16(gsrc, ldst)                                                        \
  __builtin_amdgcn_global_load_lds(                                                \
      (const __attribute__((address_space(1))) void*)(gsrc),                       \
      (__attribute__((address_space(3))) void*)(ldst), 16, 0, 0)

// ---------------- hidden_states fp32 -> bf16 ----------------
__global__ __launch_bounds__(256) void xconv(const float* __restrict__ X,
                                             unsigned short* __restrict__ XB) {
  int gid = blockIdx.x * 256 + threadIdx.x;
  float4 v = *(const float4*)&X[(size_t)gid * 4];
  ushort4 pk;
  pk.x = f2bf(v.x); pk.y = f2bf(v.y); pk.z = f2bf(v.z); pk.w = f2bf(v.w);
  *(ushort4*)&XB[(size_t)gid * 4] = pk;
}

// ---------------- skinny GEMM: [64 x K] bf16 @ W(fp32 [K][N]) -> partials ----------------
__global__ __launch_bounds__(256) void gemm_skinny(
    const unsigned short* __restrict__ A,
    const float* __restrict__ W0, const float* __restrict__ W1, const float* __restrict__ W2,
    int nw0, int nw1, int nw2,
    float* __restrict__ part, int Ntot, int kchunk) {
  __shared__ unsigned short Wt[64 * 64];
  const int nt = blockIdx.x, ks = blockIdx.y;
  const int tid = threadIdx.x, lane = tid & 63, w = tid >> 6;
  const int lr = lane & 15, lc = lane >> 4;
  const int n0 = nt * 64;
  const float* W; int wld, wcol;
  if (n0 < nw0) { W = W0; wld = nw0; wcol = n0; }
  else if (n0 < nw0 + nw1) { W = W1; wld = nw1; wcol = n0 - nw0; }
  else { W = W2; wld = nw2; wcol = n0 - nw0 - nw1; }

  f32x4 acc[4];
  #pragma unroll
  for (int mi = 0; mi < 4; ++mi)
    #pragma unroll
    for (int i = 0; i < 4; ++i) acc[mi][i] = 0.f;

  const int qn = tid & 15, qk = tid >> 4;
  const int kb0 = ks * kchunk;
  const int nkt = kchunk / 64;

  float4 wr0, wr1, wr2, wr3;
  {
    const float* wp = &W[(size_t)(kb0 + qk * 4) * wld + wcol + qn * 4];
    wr0 = *(const float4*)(wp);
    wr1 = *(const float4*)(wp + wld);
    wr2 = *(const float4*)(wp + 2 * (size_t)wld);
    wr3 = *(const float4*)(wp + 3 * (size_t)wld);
  }

  for (int kt = 0; kt < nkt; ++kt) {
    const int kb = kb0 + kt * 64;
    #pragma unroll
    for (int c = 0; c < 4; ++c) {
      const int n = qn * 4 + c;
      ushort4 pk;
      pk.x = f2bf(getc(wr0, c)); pk.y = f2bf(getc(wr1, c));
      pk.z = f2bf(getc(wr2, c)); pk.w = f2bf(getc(wr3, c));
      const int byt = n * 128 + ((qk * 8) ^ ((n & 7) << 4));
      *(ushort4*)((char*)Wt + byt) = pk;
    }
    bar_lds();
    if (kt + 1 < nkt) {
      const float* wp = &W[(size_t)(kb + 64 + qk * 4) * wld + wcol + qn * 4];
      wr0 = *(const float4*)(wp);
      wr1 = *(const float4*)(wp + wld);
      wr2 = *(const float4*)(wp + 2 * (size_t)wld);
      wr3 = *(const float4*)(wp + 3 * (size_t)wld);
    }
    #pragma unroll
    for (int kh = 0; kh < 2; ++kh) {
      const int ncol = w * 16 + lr;
      short8 bf = *(const short8*)((char*)Wt + ncol * 128 + ((kh * 64 + lc * 16) ^ ((ncol & 7) << 4)));
      const int kkg = kb + kh * 32 + lc * 8;
      #pragma unroll
      for (int mi = 0; mi < 4; ++mi) {
        short8 af = *(const short8*)&A[(size_t)(mi * 16 + lr) * 4096 + kkg];
        acc[mi] = __builtin_amdgcn_mfma_f32_16x16x32_bf16(af, bf, acc[mi], 0, 0, 0);
      }
    }
    bar_lds();
  }
  #pragma unroll
  for (int mi = 0; mi < 4; ++mi)
    #pragma unroll
    for (int i = 0; i < 4; ++i) {
      const int row = mi * 16 + lc * 4 + i;
      part[((size_t)ks * 64 + row) * Ntot + n0 + w * 16 + lr] = acc[mi][i];
    }
}

// ---------------- reduce proj partials + RoPE -> Qr bf16, K/V-new fp32 ----------------
__global__ __launch_bounds__(256) void proj_reduce(
    const float* __restrict__ part, const int* __restrict__ posids,
    unsigned short* __restrict__ QR, float* __restrict__ KF,
    float* __restrict__ VF) {
  const int gid = blockIdx.x * 256 + threadIdx.x;
  const int j = gid & 63;
  const int hh = (gid >> 6) % 48;
  const int row = gid / 3072;
  const int b = row >> 4, s = row & 15;
  int col0; bool rope;
  if (hh < 32)      { col0 = hh * 128 + j; rope = true; }
  else if (hh < 40) { col0 = 4096 + (hh - 32) * 128 + j; rope = true; }
  else              { col0 = 5120 + (hh - 40) * 128 + j; rope = false; }
  float v0 = 0.f, v1 = 0.f;
  #pragma unroll
  for (int ks = 0; ks < KSPLIT; ++ks) {
    v0 += part[((size_t)ks * 64 + row) * 6144 + col0];
    v1 += part[((size_t)ks * 64 + row) * 6144 + col0 + 64];
  }
  float o0 = v0, o1 = v1;
  if (rope) {
    const int pos = posids[row];
    const double inv = exp2(-(double)j * (13.287712379549449 / 64.0));
    double th = (double)pos * inv;
    const double TWO_PI = 6.283185307179586476925286766559;
    th -= floor(th / TWO_PI) * TWO_PI;
    float sv, cv;
    sincosf((float)th, &sv, &cv);
    o0 = v0 * cv - v1 * sv;
    o1 = v1 * cv + v0 * sv;
  }
  if (hh < 32) {
    const size_t didx = (((size_t)(b * 32 + hh) * 16 + s) * 128) + j;
    QR[didx] = f2bf(o0);
    QR[didx + 64] = f2bf(o1);
  } else if (hh < 40) {
    const size_t didx = (((size_t)(b * 8 + (hh - 32)) * 16 + s) * 128) + j;
    KF[didx] = o0;
    KF[didx + 64] = o1;
  } else {
    const size_t didx = (((size_t)(b * 8 + (hh - 40)) * 16 + s) * 128) + j;
    VF[didx] = o0;
    VF[didx + 64] = o1;
  }
}

// ---------------- flash attention: async LDS staging, depth-2, counted vmcnt ----------------
// K/V tiles staged fp32 to LDS via global_load_lds (zero VGPR cost, truly async).
// Cell-XOR swizzle (c' = c ^ (key&7) ^ ((key>>3)&3)<<1, 16B cells) applied by
// pre-swizzling the per-lane GLOBAL source address (LDS dest must stay linear);
// readers apply the same XOR -> QK^T b128 reads and PV b32 gathers conflict-free.
// fp32->bf16 conversion happens at LDS->reg read (VALU, hidden under BW bound).
__global__ __launch_bounds__(256, 2) void attn_kernel(
    const float* __restrict__ kc, const float* __restrict__ vc,
    const unsigned short* __restrict__ QR, const float* __restrict__ KF,
    const float* __restrict__ VF,
    float* __restrict__ Opart, float* __restrict__ ML) {
  __shared__ float Kf[2][TK * HD];            // 2 x 16 KB
  __shared__ float Vf[2][TK * HD];            // 2 x 16 KB
  __shared__ unsigned short Pl[4][16 * 40];   // per-wave P, row 80B (16B-aligned)

  const int split = blockIdx.x, kvh = blockIdx.y, b = blockIdx.z;
  const int tid = threadIdx.x, lane = tid & 63, w = tid >> 6;
  const int lr = lane & 15, lc = lane >> 4;

  // Q fragments: wave w = head-in-group, token = lr
  short8 qf[4];
  {
    const unsigned short* qb = QR + (((size_t)b * NH + kvh * 4 + w) * SS + lr) * HD;
    #pragma unroll
    for (int kd = 0; kd < 4; ++kd) qf[kd] = *(const short8*)(qb + kd * 32 + lc * 8);
  }

  float m_i[4], l_i[4];
  f32x4 oacc[8];
  #pragma unroll
  for (int i = 0; i < 4; ++i) { m_i[i] = -1e30f; l_i[i] = 0.f; }
  #pragma unroll
  for (int d8 = 0; d8 < 8; ++d8)
    #pragma unroll
    for (int i = 0; i < 4; ++i) oacc[d8][i] = 0.f;

  const int kbase = split * (NTILE * TK);

  // staging lane constants: chunk cw = w*4+p covers rows {2cw, 2cw+1}
  const int rA = lane >> 5;      // sub-row in chunk
  const int cpr = lane & 31;     // destination 16B-cell c'
  const float* kc_blk = kc + ((size_t)b * PAST * NKV + kvh) * HD;
  const float* vc_blk = vc + ((size_t)b * PAST * NKV + kvh) * HD;
  const float* kf_blk = KF + (((size_t)b * NKV + kvh) * SS) * HD;
  const float* vf_blk = VF + (((size_t)b * NKV + kvh) * SS) * HD;

  auto issue_tile = [&](int t, int buf) {
    const int kk0 = kbase + t * TK;
    #pragma unroll
    for (int p = 0; p < 4; ++p) {
      const int row = (w * 4 + p) * 2 + rA;
      const int sw = (row & 7) ^ (((row >> 3) & 3) << 1);
      const int d0 = (cpr ^ sw) << 2;
      const int kk = kk0 + row;
      const int ts = min(max(kk - PAST, 0), SS - 1);
      const float* sK = (kk < PAST) ? (kc_blk + (size_t)kk * (NKV * HD) + d0)
                                    : (kf_blk + (size_t)ts * HD + d0);
      GLOAD16(sK, &Kf[buf][(w * 4 + p) * 256]);
    }
    #pragma unroll
    for (int p = 0; p < 4; ++p) {
      const int row = (w * 4 + p) * 2 + rA;
      const int sw = (row & 7) ^ (((row >> 3) & 3) << 1);
      const int d0 = (cpr ^ sw) << 2;
      const int kk = kk0 + row;
      const int ts = min(max(kk - PAST, 0), SS - 1);
      const float* sV = (kk < PAST) ? (vc_blk + (size_t)kk * (NKV * HD) + d0)
                                    : (vf_blk + (size_t)ts * HD + d0);
      GLOAD16(sV, &Vf[buf][(w * 4 + p) * 256]);
    }
  };

  auto compute_tile = [&](int t, int buf) {
    const int kk0 = kbase + t * TK;
    const int nvalid = min(TK, max(0, KVLEN - kk0));
    const float* Kb = &Kf[buf][0];
    const float* Vb = &Vf[buf][0];

    // ---- QK^T (K read from swizzled fp32 LDS, cvt to bf16 in regs) ----
    f32x4 sacc[2];
    #pragma unroll
    for (int nb = 0; nb < 2; ++nb)
      #pragma unroll
      for (int i = 0; i < 4; ++i) sacc[nb][i] = 0.f;
    #pragma unroll
    for (int nb = 0; nb < 2; ++nb) {
      const int key = nb * 16 + lr;
      const int sw = (key & 7) ^ (((key >> 3) & 3) << 1);
      const float* kr = Kb + key * HD;
      #pragma unroll
      for (int kd = 0; kd < 4; ++kd) {
        const int c0 = kd * 8 + lc * 2;
        const float4 fA = *(const float4*)(kr + ((c0 ^ sw) << 2));
        const float4 fB = *(const float4*)(kr + (((c0 + 1) ^ sw) << 2));
        union { unsigned u[4]; short8 v; } tm;
        tm.u[0] = pk2bf(fA.x, fA.y); tm.u[1] = pk2bf(fA.z, fA.w);
        tm.u[2] = pk2bf(fB.x, fB.y); tm.u[3] = pk2bf(fB.z, fB.w);
        sacc[nb] = __builtin_amdgcn_mfma_f32_16x16x32_bf16(qf[kd], tm.v, sacc[nb], 0, 0, 0);
      }
    }

    // ---- online softmax (row s = lc*4+i, key col = nb*16+lr) ----
    const float scl = 0.08838834764831845f;
    float resc[4];
    #pragma unroll
    for (int i = 0; i < 4; ++i) {
      const int s = lc * 4 + i;
      const int k0 = kk0 + lr, k1 = kk0 + 16 + lr;
      const bool ok0 = (lr < nvalid) && (k0 <= PAST + s);
      const bool ok1 = (16 + lr < nvalid) && (k1 <= PAST + s);
      float vv0 = ok0 ? sacc[0][i] * scl : -1e30f;
      float vv1 = ok1 ? sacc[1][i] * scl : -1e30f;
      float mx = fmaxf(vv0, vv1);
      mx = fmaxf(mx, __shfl_xor(mx, 1));
      mx = fmaxf(mx, __shfl_xor(mx, 2));
      mx = fmaxf(mx, __shfl_xor(mx, 4));
      mx = fmaxf(mx, __shfl_xor(mx, 8));
      const float mnew = fmaxf(m_i[i], mx);
      const float rs = __expf(m_i[i] - mnew);
      float p0 = __expf(vv0 - mnew), p1 = __expf(vv1 - mnew);
      float sum = p0 + p1;
      sum += __shfl_xor(sum, 1);
      sum += __shfl_xor(sum, 2);
      sum += __shfl_xor(sum, 4);
      sum += __shfl_xor(sum, 8);
      l_i[i] = l_i[i] * rs + sum;
      m_i[i] = mnew;
      resc[i] = rs;
      unsigned short* prow = &Pl[w][s * 40];
      prow[lr] = f2bf(p0);
      prow[16 + lr] = f2bf(p1);
    }
    #pragma unroll
    for (int d8 = 0; d8 < 8; ++d8)
      #pragma unroll
      for (int i = 0; i < 4; ++i) oacc[d8][i] *= resc[i];

    wait_lds();  // Pl[w] is wave-private; DS-retire only

    // ---- PV (V gathered from swizzled fp32 LDS, cvt to bf16) ----
    short8 pf = *(const short8*)&Pl[w][lr * 40 + lc * 8];
    int swv[8];
    #pragma unroll
    for (int j = 0; j < 8; ++j) swv[j] = j ^ (lc << 1);
    #pragma unroll
    for (int db = 0; db < 8; ++db) {
      const int cb = db * 4 + (lr >> 2);
      float fj[8];
      #pragma unroll
      for (int j = 0; j < 8; ++j) {
        const int key = lc * 8 + j;
        fj[j] = Vb[(size_t)key * HD + (((cb ^ swv[j]) << 2) + (lr & 3))];
      }
      union { unsigned u[4]; short8 v; } tv;
      tv.u[0] = pk2bf(fj[0], fj[1]); tv.u[1] = pk2bf(fj[2], fj[3]);
      tv.u[2] = pk2bf(fj[4], fj[5]); tv.u[3] = pk2bf(fj[6], fj[7]);
      oacc[db] = __builtin_amdgcn_mfma_f32_16x16x32_bf16(pf, tv.v, oacc[db], 0, 0, 0);
    }
  };

  // ---- prologue: tiles 0,1 in flight ----
  issue_tile(0, 0);
  issue_tile(1, 1);
  asm volatile("s_waitcnt vmcnt(8)" ::: "memory");  // tile 0 landed (8 = tile 1's)
  __builtin_amdgcn_s_barrier();
  asm volatile("" ::: "memory");

  for (int t = 0; t < NTILE; ++t) {
    const int buf = t & 1;
    compute_tile(t, buf);
    __builtin_amdgcn_s_barrier();   // all waves done reading buf
    asm volatile("" ::: "memory");
    if (t < NTILE - 2) {
      issue_tile(t + 2, buf);       // refill the buffer just freed
      asm volatile("s_waitcnt vmcnt(8)" ::: "memory");  // t+1's loads landed
    } else {
      asm volatile("s_waitcnt vmcnt(0)" ::: "memory");
    }
    __builtin_amdgcn_s_barrier();   // everyone's t+1 loads landed
    asm volatile("" ::: "memory");
  }

  // ---- epilogue: partial O, m, l ----
  const size_t pbase = (((size_t)b * NKV + kvh) * NSPLIT + split) * 64;
  #pragma unroll
  for (int db = 0; db < 8; ++db)
    #pragma unroll
    for (int i = 0; i < 4; ++i) {
      const int row = w * 16 + lc * 4 + i;
      Opart[(pbase + row) * HD + db * 16 + lr] = oacc[db][i];
    }
  if (lr == 0) {
    #pragma unroll
    for (int i = 0; i < 4; ++i) {
      const int row = w * 16 + lc * 4 + i;
      ML[(pbase + row) * 2] = m_i[i];
      ML[(pbase + row) * 2 + 1] = l_i[i];
    }
  }
}

// ---------------- combine split-softmax partials -> attn bf16 [64][4096] ----------------
__global__ __launch_bounds__(128) void combine(const float* __restrict__ Opart,
                                               const float* __restrict__ ML,
                                               unsigned short* __restrict__ AT) {
  const int rid = blockIdx.x;
  const int d = threadIdx.x;
  const int s = rid & 15, h = (rid >> 4) & 31, b = rid >> 9;
  const int kvh = h >> 2, g = h & 3;
  const int prow = g * 16 + s;
  const size_t base = ((size_t)b * NKV + kvh) * NSPLIT;
  float ms[NSPLIT], ls[NSPLIT];
  float M = -1e30f;
  #pragma unroll
  for (int sp = 0; sp < NSPLIT; ++sp) {
    ms[sp] = ML[((base + sp) * 64 + prow) * 2];
    ls[sp] = ML[((base + sp) * 64 + prow) * 2 + 1];
    M = fmaxf(M, ms[sp]);
  }
  float denom = 0.f, acc = 0.f;
  #pragma unroll
  for (int sp = 0; sp < NSPLIT; ++sp) {
    const float e = __expf(ms[sp] - M);
    denom += ls[sp] * e;
    acc += e * Opart[((base + sp) * 64 + prow) * HD + d];
  }
  AT[((size_t)(b * 16 + s)) * 4096 + h * 128 + d] = f2bf(acc / denom);
}

// ---------------- reduce Wo partials -> fp32 out ----------------
__global__ __launch_bounds__(256) void wo_reduce(const float* __restrict__ part,
                                                 float* __restrict__ out) {
  const int gid = blockIdx.x * 256 + threadIdx.x;
  float4 s = {0, 0, 0, 0};
  #pragma unroll
  for (int ks = 0; ks < KSPLIT; ++ks) {
    const float4 v = *(const float4*)&part[(size_t)ks * 262144 + (size_t)gid * 4];
    s.x += v.x; s.y += v.y; s.z += v.z; s.w += v.w;
  }
  *(float4*)&out[(size_t)gid * 4] = s;
}

extern "C" void kernel_launch(void* const* d_in, const int* in_sizes, int n_in,
                              void* d_out, int out_size, void* d_ws, size_t ws_size,
                              hipStream_t stream) {
  (void)in_sizes; (void)n_in; (void)out_size; (void)ws_size;
  const float* hs = (const float*)d_in[0];
  const float* kc = (const float*)d_in[1];
  const float* vc = (const float*)d_in[2];
  const float* Wq = (const float*)d_in[3];
  const float* Wk = (const float*)d_in[4];
  const float* Wv = (const float*)d_in[5];
  const float* Wo = (const float*)d_in[6];
  const int* pos = (const int*)d_in[7];
  float* out = (float*)d_out;
  char* ws = (char*)d_ws;

  unsigned short* XB = (unsigned short*)(ws);              // 512 KB
  unsigned short* QR = (unsigned short*)(ws + 0x080000);   // 512 KB
  float* KF = (float*)(ws + 0x100000);                     // 256 KB fp32 new-K
  float* VF = (float*)(ws + 0x140000);                     // 256 KB fp32 new-V
  unsigned short* AT = (unsigned short*)(ws + 0x180000);   // 512 KB
  float* RED = (float*)(ws + 0x200000);                    // gemm partials / Opart (18.9 MB)
  float* ML  = (float*)(ws + 0x1600000);                   // 288 KB

  hipLaunchKernelGGL(xconv, dim3(256), dim3(256), 0, stream, hs, XB);
  hipLaunchKernelGGL(gemm_skinny, dim3(96, KSPLIT), dim3(256), 0, stream,
                     XB, Wq, Wk, Wv, 4096, 1024, 1024, RED, 6144, 4096 / KSPLIT);
  hipLaunchKernelGGL(proj_reduce, dim3(768), dim3(256), 0, stream, RED, pos, QR, KF, VF);
  hipLaunchKernelGGL(attn_kernel, dim3(NSPLIT, NKV, BB), dim3(256), 0, stream,
                     kc, vc, QR, KF, VF, RED, ML);
  hipLaunchKernelGGL(combine, dim3(2048), dim3(128), 0, stream, RED, ML, AT);
  hipLaunchKernelGGL(gemm_skinny, dim3(64, KSPLIT), dim3(256), 0, stream,
                     AT, Wo, Wo, Wo, 4096, 0, 0, RED, 4096, 4096 / KSPLIT);
  hipLaunchKernelGGL(wo_reduce, dim3(256), dim3(256), 0, stream, RED, out);
}